// Round 2
// baseline (17822.528 us; speedup 1.0000x reference)
//
#include <hip/hip_runtime.h>
#include <math.h>

#define Bn 1024
#define Dn 512
#define Hn 512
#define Vn 8192
#define Tn 20
#define G4 2048

// ---------------- threefry2x32 (JAX-exact, 20 rounds) ----------------
__host__ __device__ __forceinline__ void threefry2x32(
    unsigned k0, unsigned k1, unsigned x0, unsigned x1,
    unsigned& y0, unsigned& y1) {
  unsigned ks2 = k0 ^ k1 ^ 0x1BD11BDAu;
#define TF_RND(r) { x0 += x1; x1 = (x1 << (r)) | (x1 >> (32 - (r))); x1 ^= x0; }
  x0 += k0; x1 += k1;
  TF_RND(13) TF_RND(15) TF_RND(26) TF_RND(6)
  x0 += k1; x1 += ks2 + 1u;
  TF_RND(17) TF_RND(29) TF_RND(16) TF_RND(24)
  x0 += ks2; x1 += k0 + 2u;
  TF_RND(13) TF_RND(15) TF_RND(26) TF_RND(6)
  x0 += k0; x1 += k1 + 3u;
  TF_RND(17) TF_RND(29) TF_RND(16) TF_RND(24)
  x0 += k1; x1 += ks2 + 4u;
  TF_RND(13) TF_RND(15) TF_RND(26) TF_RND(6)
  x0 += ks2; x1 += k0 + 5u;
#undef TF_RND
  y0 = x0; y1 = x1;
}

// ---------------- init: h0 = relu(img @ fc1_w^T + b), c=x=0, mask=1 ----------------
__global__ void k_init(const float* __restrict__ img, const float* __restrict__ fc1w,
                       const float* __restrict__ fc1b,
                       float* __restrict__ h, float* __restrict__ c,
                       float* __restrict__ x, float* __restrict__ mask) {
  int idx = blockIdx.x * blockDim.x + threadIdx.x;  // B*H
  int b = idx >> 9, u = idx & 511;
  const float4* xr = (const float4*)(img + (size_t)b * Dn);
  const float4* wr = (const float4*)(fc1w + (size_t)u * Dn);
  double acc = 0.0;
  for (int k = 0; k < Dn / 4; ++k) {
    float4 a = xr[k], w = wr[k];
    acc = fma((double)a.x, (double)w.x, acc);
    acc = fma((double)a.y, (double)w.y, acc);
    acc = fma((double)a.z, (double)w.z, acc);
    acc = fma((double)a.w, (double)w.w, acc);
  }
  acc += (double)fc1b[u];
  float hv = (float)acc;
  h[idx] = hv > 0.f ? hv : 0.f;
  c[idx] = 0.f;
  x[idx] = 0.f;
  if (u == 0) mask[b] = 1.f;
}

// ---------------- gates = x@wih^T + bih + h@whh^T + bhh (f64 acc, 16x16 tile) ----------------
__global__ void __launch_bounds__(256) k_gates(
    const float* __restrict__ x, const float* __restrict__ h,
    const float* __restrict__ wih, const float* __restrict__ whh,
    const float* __restrict__ bih, const float* __restrict__ bhh,
    float* __restrict__ gates) {
  __shared__ float as[16][33];
  __shared__ float ws[16][33];
  int bb = (blockIdx.x >> 7) << 4;   // G4/16 = 128 row-blocks
  int rr = (blockIdx.x & 127) << 4;
  int tb = threadIdx.x >> 4, tr = threadIdx.x & 15;
  double acc0 = 0.0, acc1 = 0.0;
  // pass 1: x @ wih^T
  for (int k0 = 0; k0 < Hn; k0 += 32) {
    for (int i = threadIdx.x; i < 512; i += 256) {
      int r = i >> 5, cc = i & 31;
      as[r][cc] = x[(size_t)(bb + r) * Hn + k0 + cc];
      ws[r][cc] = wih[(size_t)(rr + r) * Hn + k0 + cc];
    }
    __syncthreads();
#pragma unroll
    for (int cc = 0; cc < 32; cc += 2) {
      acc0 = fma((double)as[tb][cc], (double)ws[tr][cc], acc0);
      acc1 = fma((double)as[tb][cc + 1], (double)ws[tr][cc + 1], acc1);
    }
    __syncthreads();
  }
  // pass 2: h @ whh^T
  for (int k0 = 0; k0 < Hn; k0 += 32) {
    for (int i = threadIdx.x; i < 512; i += 256) {
      int r = i >> 5, cc = i & 31;
      as[r][cc] = h[(size_t)(bb + r) * Hn + k0 + cc];
      ws[r][cc] = whh[(size_t)(rr + r) * Hn + k0 + cc];
    }
    __syncthreads();
#pragma unroll
    for (int cc = 0; cc < 32; cc += 2) {
      acc0 = fma((double)as[tb][cc], (double)ws[tr][cc], acc0);
      acc1 = fma((double)as[tb][cc + 1], (double)ws[tr][cc + 1], acc1);
    }
    __syncthreads();
  }
  double acc = acc0 + acc1 + (double)bih[rr + tr] + (double)bhh[rr + tr];
  gates[(size_t)(bb + tb) * G4 + rr + tr] = (float)acc;
}

// ---------------- LSTM cell pointwise update ----------------
__global__ void k_update(const float* __restrict__ gates, float* __restrict__ c,
                         float* __restrict__ hout) {
  int idx = blockIdx.x * blockDim.x + threadIdx.x;  // B*H
  int b = idx >> 9, u = idx & 511;
  const float* gr = gates + (size_t)b * G4;
  float gi = gr[u], gf = gr[Hn + u], gg = gr[2 * Hn + u], go = gr[3 * Hn + u];
  double si = 1.0 / (1.0 + exp(-(double)gi));
  double sf = 1.0 / (1.0 + exp(-(double)gf));
  double tg = tanh((double)gg);
  double so = 1.0 / (1.0 + exp(-(double)go));
  double cold = (double)c[idx];
  float cn = (float)(sf * cold + si * tg);
  c[idx] = cn;
  hout[idx] = (float)(so * tanh((double)cn));
}

// ---------------- logits = h@out_w^T + out_b (f64 acc, 16x16 tile) ----------------
__global__ void __launch_bounds__(256) k_logits(
    const float* __restrict__ h, const float* __restrict__ outw,
    const float* __restrict__ outb, float* __restrict__ logits) {
  __shared__ float as[16][33];
  __shared__ float ws[16][33];
  int bb = (blockIdx.x >> 9) << 4;   // V/16 = 512 row-blocks
  int rr = (blockIdx.x & 511) << 4;
  int tb = threadIdx.x >> 4, tr = threadIdx.x & 15;
  double acc0 = 0.0, acc1 = 0.0;
  for (int k0 = 0; k0 < Hn; k0 += 32) {
    for (int i = threadIdx.x; i < 512; i += 256) {
      int r = i >> 5, cc = i & 31;
      as[r][cc] = h[(size_t)(bb + r) * Hn + k0 + cc];
      ws[r][cc] = outw[(size_t)(rr + r) * Hn + k0 + cc];
    }
    __syncthreads();
#pragma unroll
    for (int cc = 0; cc < 32; cc += 2) {
      acc0 = fma((double)as[tb][cc], (double)ws[tr][cc], acc0);
      acc1 = fma((double)as[tb][cc + 1], (double)ws[tr][cc + 1], acc1);
    }
    __syncthreads();
  }
  double acc = acc0 + acc1 + (double)outb[rr + tr];
  logits[(size_t)(bb + tb) * Vn + rr + tr] = (float)acc;
}

// ---------------- fused softmax + gumbel-argmax + outputs (one block per row) ----------------
// Partitionable threefry (JAX >= 0.4.30 default):
//   bits(j) = y0 ^ y1,  (y0,y1) = threefry2x32(step_key, x0 = 0 (hi), x1 = j (lo)),
//   j = b*V + v (64-bit row-major iota, hi word always 0 here since B*V < 2^32).
__global__ void __launch_bounds__(256) k_sm(
    const float* __restrict__ logits, const float* __restrict__ mask,
    float* __restrict__ out_base, int* __restrict__ action,
    unsigned k0, unsigned k1, int t) {
  __shared__ __align__(16) float row[Vn];
  __shared__ float rf[256];
  __shared__ int ri[256];
  __shared__ double rd[256];
  int b = blockIdx.x, tid = threadIdx.x;
  const float4* src = (const float4*)(logits + (size_t)b * Vn);
  float4* dst = (float4*)row;
  for (int i = tid; i < Vn / 4; i += 256) dst[i] = src[i];
  __syncthreads();

  // pass 1: row max + gumbel argmax (first-index tiebreak)
  float m = -INFINITY, best = -INFINITY;
  int bidx = Vn;
  for (int v = tid; v < Vn; v += 256) {
    float lg = row[v];
    m = fmaxf(m, lg);
    unsigned j = (unsigned)(b * Vn + v);
    unsigned y0, y1;
    threefry2x32(k0, k1, 0u, j, y0, y1);
    unsigned bits = y0 ^ y1;
    float uf = __uint_as_float((bits >> 9) | 0x3F800000u) - 1.0f;
    uf = fmaxf(uf, 1.17549435e-38f);           // u = max(tiny, f)
    float inner = (float)(-log((double)uf));    // f32-rounded inner -log(u)
    float g = (float)(-log((double)inner));     // f32-rounded gumbel
    float val = lg + g;
    if (val > best) { best = val; bidx = v; }   // ascending v -> first max kept
  }
  rf[tid] = m;
  __syncthreads();
  for (int s = 128; s > 0; s >>= 1) {
    if (tid < s) rf[tid] = fmaxf(rf[tid], rf[tid + s]);
    __syncthreads();
  }
  float rowmax = rf[0];
  __syncthreads();
  rf[tid] = best; ri[tid] = bidx;
  __syncthreads();
  for (int s = 128; s > 0; s >>= 1) {
    if (tid < s) {
      float v2 = rf[tid + s]; int i2 = ri[tid + s];
      if (v2 > rf[tid] || (v2 == rf[tid] && i2 < ri[tid])) { rf[tid] = v2; ri[tid] = i2; }
    }
    __syncthreads();
  }
  int act = ri[0];

  // pass 2: sum exp(x - m) in f64
  double sacc = 0.0;
  for (int v = tid; v < Vn; v += 256) sacc += exp((double)(row[v] - rowmax));
  rd[tid] = sacc;
  __syncthreads();
  for (int s = 128; s > 0; s >>= 1) {
    if (tid < s) rd[tid] += rd[tid + s];
    __syncthreads();
  }
  double lse = log(rd[0]);
  float mk = mask[b];
  __syncthreads();

  // pass 3: logp, p, probs, entropy, lp
  float* probs = out_base + 3 * Bn * Tn + ((size_t)(b * Tn + t)) * Vn;
  double entacc = 0.0;
  for (int v = tid; v < Vn; v += 256) {
    float sh = row[v] - rowmax;
    float logp = (float)((double)sh - lse);
    float p = (float)exp((double)logp);
    probs[v] = p * mk;
    entacc += (double)(p * logp);
    if (v == act) out_base[Bn * Tn + b * Tn + t] = logp * mk;  // lps
  }
  rd[tid] = entacc;
  __syncthreads();
  for (int s = 128; s > 0; s >>= 1) {
    if (tid < s) rd[tid] += rd[tid + s];
    __syncthreads();
  }
  if (tid == 0) {
    out_base[2 * Bn * Tn + b * Tn + t] = (float)(-rd[0]) * mk;  // ents
    out_base[b * Tn + t] = (float)act;                          // msgs
    action[b] = act;
  }
}

// ---------------- next input: x = emb[action], mask update (eos=0) ----------------
__global__ void k_next(const float* __restrict__ emb, const int* __restrict__ action,
                       float* __restrict__ x, float* __restrict__ mask) {
  int idx = blockIdx.x * blockDim.x + threadIdx.x;  // B*H
  int b = idx >> 9, u = idx & 511;
  int a = action[b];
  x[idx] = emb[(size_t)a * Hn + u];
  if (u == 0) mask[b] = mask[b] * (a == 0 ? 0.f : 1.f);
}

extern "C" void kernel_launch(void* const* d_in, const int* in_sizes, int n_in,
                              void* d_out, int out_size, void* d_ws, size_t ws_size,
                              hipStream_t stream) {
  const float* img  = (const float*)d_in[0];
  const float* emb  = (const float*)d_in[1];
  const float* fc1w = (const float*)d_in[2];
  const float* fc1b = (const float*)d_in[3];
  const float* wih  = (const float*)d_in[4];
  const float* whh  = (const float*)d_in[5];
  const float* bih  = (const float*)d_in[6];
  const float* bhh  = (const float*)d_in[7];
  const float* outw = (const float*)d_in[8];
  const float* outb = (const float*)d_in[9];
  float* out = (float*)d_out;

  float* ws = (float*)d_ws;
  float* hA    = ws;                 // B*H
  float* hB    = hA + Bn * Hn;       // B*H
  float* c     = hB + Bn * Hn;       // B*H
  float* x     = c  + Bn * Hn;       // B*H
  float* mask  = x  + Bn * Hn;       // B
  int*   action = (int*)(mask + Bn); // B
  float* gates = (float*)(action + Bn);   // B*4H
  float* logits = gates + (size_t)Bn * G4; // B*V

  // step keys: fold-like split (jax_threefry_partitionable=True, JAX >= 0.4.30):
  // keys[t] = threefry2x32(key=(0,42), x0=0 (iota hi word), x1=t (iota lo word))
  unsigned kk0[Tn], kk1[Tn];
  for (int i = 0; i < Tn; ++i) {
    unsigned y0, y1;
    threefry2x32(0u, 42u, 0u, (unsigned)i, y0, y1);
    kk0[i] = y0; kk1[i] = y1;
  }

  k_init<<<(Bn * Hn) / 256, 256, 0, stream>>>(img, fc1w, fc1b, hA, c, x, mask);

  for (int t = 0; t < Tn; ++t) {
    const float* hin = (t & 1) ? hB : hA;
    float* hout = (t & 1) ? hA : hB;
    k_gates<<<(Bn / 16) * (G4 / 16), 256, 0, stream>>>(x, hin, wih, whh, bih, bhh, gates);
    k_update<<<(Bn * Hn) / 256, 256, 0, stream>>>(gates, c, hout);
    k_logits<<<(Bn / 16) * (Vn / 16), 256, 0, stream>>>(hout, outw, outb, logits);
    k_sm<<<Bn, 256, 0, stream>>>(logits, mask, out, action, kk0[t], kk1[t], t);
    k_next<<<(Bn * Hn) / 256, 256, 0, stream>>>(emb, action, x, mask);
  }
}

// Round 3
// 5968.130 us; speedup vs baseline: 2.9863x; 2.9863x over previous
//
#include <hip/hip_runtime.h>
#include <math.h>

#define Bn 1024
#define Dn 512
#define Hn 512
#define Vn 8192
#define Tn 20
#define G4 2048

// ---------------- threefry2x32 (JAX-exact, 20 rounds) ----------------
__host__ __device__ __forceinline__ void threefry2x32(
    unsigned k0, unsigned k1, unsigned x0, unsigned x1,
    unsigned& y0, unsigned& y1) {
  unsigned ks2 = k0 ^ k1 ^ 0x1BD11BDAu;
#define TF_RND(r) { x0 += x1; x1 = (x1 << (r)) | (x1 >> (32 - (r))); x1 ^= x0; }
  x0 += k0; x1 += k1;
  TF_RND(13) TF_RND(15) TF_RND(26) TF_RND(6)
  x0 += k1; x1 += ks2 + 1u;
  TF_RND(17) TF_RND(29) TF_RND(16) TF_RND(24)
  x0 += ks2; x1 += k0 + 2u;
  TF_RND(13) TF_RND(15) TF_RND(26) TF_RND(6)
  x0 += k0; x1 += k1 + 3u;
  TF_RND(17) TF_RND(29) TF_RND(16) TF_RND(24)
  x0 += k1; x1 += ks2 + 4u;
  TF_RND(13) TF_RND(15) TF_RND(26) TF_RND(6)
  x0 += ks2; x1 += k0 + 5u;
#undef TF_RND
  y0 = x0; y1 = x1;
}

// ---------------- f32 register-tiled GEMM core: C[128x64] = A[128xK] * W[64xK]^T ----
// As[16][132]/Bs[16][68]: padded so staging writes are 2-way (free) and compute
// reads are broadcast (As) / 2-way (Bs). 8x4 outputs per thread, 256 threads.
__device__ __forceinline__ void gemm_seg(
    const float* __restrict__ A, int lda, const float* __restrict__ W, int ldw,
    int bm, int bn, int tid, int tm8, int tn4,
    float (*As)[132], float (*Bs)[68], float acc[8][4]) {
  for (int k0 = 0; k0 < 512; k0 += 16) {
#pragma unroll
    for (int it = 0; it < 2; ++it) {
      int g = (it << 8) + tid;
      int m = g >> 2, kq = g & 3;
      const float4 v = *(const float4*)(A + (size_t)(bm + m) * lda + k0 + (kq << 2));
      As[(kq << 2) + 0][m] = v.x; As[(kq << 2) + 1][m] = v.y;
      As[(kq << 2) + 2][m] = v.z; As[(kq << 2) + 3][m] = v.w;
    }
    {
      int m = tid >> 2, kq = tid & 3;
      const float4 v = *(const float4*)(W + (size_t)(bn + m) * ldw + k0 + (kq << 2));
      Bs[(kq << 2) + 0][m] = v.x; Bs[(kq << 2) + 1][m] = v.y;
      Bs[(kq << 2) + 2][m] = v.z; Bs[(kq << 2) + 3][m] = v.w;
    }
    __syncthreads();
#pragma unroll
    for (int k = 0; k < 16; ++k) {
      const float4 a0 = *(const float4*)&As[k][tm8];
      const float4 a1 = *(const float4*)&As[k][tm8 + 4];
      const float4 bv = *(const float4*)&Bs[k][tn4];
      float av[8] = {a0.x, a0.y, a0.z, a0.w, a1.x, a1.y, a1.z, a1.w};
      float bw[4] = {bv.x, bv.y, bv.z, bv.w};
#pragma unroll
      for (int i = 0; i < 8; ++i)
#pragma unroll
        for (int j = 0; j < 4; ++j)
          acc[i][j] = fmaf(av[i], bw[j], acc[i][j]);
    }
    __syncthreads();
  }
}

#define TILE_PROLOGUE                       \
  __shared__ float As[16][132];             \
  __shared__ float Bs[16][68];              \
  int tid = threadIdx.x;                    \
  int tm8 = (tid >> 4) << 3;                \
  int tn4 = (tid & 15) << 2;                \
  float acc[8][4] = {};

// ---------------- init: h0 = relu(img @ fc1_w^T + b); also c=x=0 ----------------
__global__ void __launch_bounds__(256) k_fc1(
    const float* __restrict__ img, const float* __restrict__ fc1w,
    const float* __restrict__ fc1b,
    float* __restrict__ h, float* __restrict__ c, float* __restrict__ x) {
  int bm = (blockIdx.x >> 3) << 7;   // 8 m-blocks
  int bn = (blockIdx.x & 7) << 6;    // 8 n-blocks (H=512)
  TILE_PROLOGUE
  gemm_seg(img, Dn, fc1w, Dn, bm, bn, tid, tm8, tn4, As, Bs, acc);
  const float4 b4 = *(const float4*)(fc1b + bn + tn4);
#pragma unroll
  for (int i = 0; i < 8; ++i) {
    size_t off = (size_t)(bm + tm8 + i) * Hn + bn + tn4;
    float4 o;
    o.x = fmaxf(acc[i][0] + b4.x, 0.f);
    o.y = fmaxf(acc[i][1] + b4.y, 0.f);
    o.z = fmaxf(acc[i][2] + b4.z, 0.f);
    o.w = fmaxf(acc[i][3] + b4.w, 0.f);
    *(float4*)(h + off) = o;
    float4 z = {0.f, 0.f, 0.f, 0.f};
    *(float4*)(c + off) = z;
    *(float4*)(x + off) = z;
  }
}

__global__ void k_mask(float* __restrict__ mask) {
  int i = blockIdx.x * blockDim.x + threadIdx.x;
  if (i < Bn) mask[i] = 1.f;
}

// ---------------- gates = x@wih^T + bih + h@whh^T + bhh ----------------
__global__ void __launch_bounds__(256) k_gates(
    const float* __restrict__ x, const float* __restrict__ h,
    const float* __restrict__ wih, const float* __restrict__ whh,
    const float* __restrict__ bih, const float* __restrict__ bhh,
    float* __restrict__ gates) {
  int bm = (blockIdx.x >> 5) << 7;   // 8 m-blocks
  int bn = (blockIdx.x & 31) << 6;   // 32 n-blocks (G4=2048)
  TILE_PROLOGUE
  gemm_seg(x, Hn, wih, Hn, bm, bn, tid, tm8, tn4, As, Bs, acc);
  gemm_seg(h, Hn, whh, Hn, bm, bn, tid, tm8, tn4, As, Bs, acc);
  const float4 bi4 = *(const float4*)(bih + bn + tn4);
  const float4 bh4 = *(const float4*)(bhh + bn + tn4);
#pragma unroll
  for (int i = 0; i < 8; ++i) {
    float4 o;
    o.x = (acc[i][0] + bi4.x) + bh4.x;
    o.y = (acc[i][1] + bi4.y) + bh4.y;
    o.z = (acc[i][2] + bi4.z) + bh4.z;
    o.w = (acc[i][3] + bi4.w) + bh4.w;
    *(float4*)(gates + (size_t)(bm + tm8 + i) * G4 + bn + tn4) = o;
  }
}

// ---------------- LSTM cell pointwise update ----------------
__global__ void k_update(const float* __restrict__ gates, float* __restrict__ c,
                         float* __restrict__ hout) {
  int idx = blockIdx.x * blockDim.x + threadIdx.x;  // B*H
  int b = idx >> 9, u = idx & 511;
  const float* gr = gates + (size_t)b * G4;
  float gi = gr[u], gf = gr[Hn + u], gg = gr[2 * Hn + u], go = gr[3 * Hn + u];
  double si = 1.0 / (1.0 + exp(-(double)gi));
  double sf = 1.0 / (1.0 + exp(-(double)gf));
  double tg = tanh((double)gg);
  double so = 1.0 / (1.0 + exp(-(double)go));
  double cold = (double)c[idx];
  float cn = (float)(sf * cold + si * tg);
  c[idx] = cn;
  hout[idx] = (float)(so * tanh((double)cn));
}

// ---------------- logits = h@out_w^T + out_b ----------------
__global__ void __launch_bounds__(256) k_logits(
    const float* __restrict__ h, const float* __restrict__ outw,
    const float* __restrict__ outb, float* __restrict__ logits) {
  int bm = (blockIdx.x >> 7) << 7;   // 8 m-blocks
  int bn = (blockIdx.x & 127) << 6;  // 128 n-blocks (V=8192)
  TILE_PROLOGUE
  gemm_seg(h, Hn, outw, Hn, bm, bn, tid, tm8, tn4, As, Bs, acc);
  const float4 b4 = *(const float4*)(outb + bn + tn4);
#pragma unroll
  for (int i = 0; i < 8; ++i) {
    float4 o;
    o.x = acc[i][0] + b4.x;
    o.y = acc[i][1] + b4.y;
    o.z = acc[i][2] + b4.z;
    o.w = acc[i][3] + b4.w;
    *(float4*)(logits + (size_t)(bm + tm8 + i) * Vn + bn + tn4) = o;
  }
}

// ---------------- fused softmax + gumbel-argmax + outputs (one block per row) ----------------
// Partitionable threefry: bits(j) = y0 ^ y1, (y0,y1) = threefry(step_key, 0, j), j = b*V+v.
__global__ void __launch_bounds__(256) k_sm(
    const float* __restrict__ logits, const float* __restrict__ mask,
    float* __restrict__ out_base, int* __restrict__ action,
    unsigned k0, unsigned k1, int t) {
  __shared__ __align__(16) float row[Vn];
  __shared__ float rf[256];
  __shared__ int ri[256];
  __shared__ double rd[256];
  int b = blockIdx.x, tid = threadIdx.x;
  const float4* src = (const float4*)(logits + (size_t)b * Vn);
  float4* dst = (float4*)row;
  for (int i = tid; i < Vn / 4; i += 256) dst[i] = src[i];
  __syncthreads();

  // pass 1: row max + gumbel argmax (first-index tiebreak)
  float m = -INFINITY, best = -INFINITY;
  int bidx = Vn;
  for (int v = tid; v < Vn; v += 256) {
    float lg = row[v];
    m = fmaxf(m, lg);
    unsigned j = (unsigned)(b * Vn + v);
    unsigned y0, y1;
    threefry2x32(k0, k1, 0u, j, y0, y1);
    unsigned bits = y0 ^ y1;
    float uf = __uint_as_float((bits >> 9) | 0x3F800000u) - 1.0f;
    uf = fmaxf(uf, 1.17549435e-38f);           // u = max(tiny, f)
    float inner = (float)(-log((double)uf));    // f32-rounded inner -log(u)
    float g = (float)(-log((double)inner));     // f32-rounded gumbel
    float val = lg + g;
    if (val > best) { best = val; bidx = v; }   // ascending v -> first max kept
  }
  rf[tid] = m;
  __syncthreads();
  for (int s = 128; s > 0; s >>= 1) {
    if (tid < s) rf[tid] = fmaxf(rf[tid], rf[tid + s]);
    __syncthreads();
  }
  float rowmax = rf[0];
  __syncthreads();
  rf[tid] = best; ri[tid] = bidx;
  __syncthreads();
  for (int s = 128; s > 0; s >>= 1) {
    if (tid < s) {
      float v2 = rf[tid + s]; int i2 = ri[tid + s];
      if (v2 > rf[tid] || (v2 == rf[tid] && i2 < ri[tid])) { rf[tid] = v2; ri[tid] = i2; }
    }
    __syncthreads();
  }
  int act = ri[0];

  // pass 2: sum exp(x - m), f32 exp + f64 adds
  double sacc = 0.0;
  for (int v = tid; v < Vn; v += 256) sacc += (double)expf(row[v] - rowmax);
  rd[tid] = sacc;
  __syncthreads();
  for (int s = 128; s > 0; s >>= 1) {
    if (tid < s) rd[tid] += rd[tid + s];
    __syncthreads();
  }
  double lse = log(rd[0]);
  float mk = mask[b];
  __syncthreads();

  // pass 3: logp, p, probs, entropy, lp
  float* probs = out_base + 3 * Bn * Tn + ((size_t)(b * Tn + t)) * Vn;
  double entacc = 0.0;
  for (int v = tid; v < Vn; v += 256) {
    float sh = row[v] - rowmax;
    float logp = (float)((double)sh - lse);
    float p = expf(logp);
    probs[v] = p * mk;
    entacc += (double)(p * logp);
    if (v == act) out_base[Bn * Tn + b * Tn + t] = logp * mk;  // lps
  }
  rd[tid] = entacc;
  __syncthreads();
  for (int s = 128; s > 0; s >>= 1) {
    if (tid < s) rd[tid] += rd[tid + s];
    __syncthreads();
  }
  if (tid == 0) {
    out_base[2 * Bn * Tn + b * Tn + t] = (float)(-rd[0]) * mk;  // ents
    out_base[b * Tn + t] = (float)act;                          // msgs
    action[b] = act;
  }
}

// ---------------- next input: x = emb[action], mask update (eos=0) ----------------
__global__ void k_next(const float* __restrict__ emb, const int* __restrict__ action,
                       float* __restrict__ x, float* __restrict__ mask) {
  int idx = blockIdx.x * blockDim.x + threadIdx.x;  // B*H
  int b = idx >> 9, u = idx & 511;
  int a = action[b];
  x[idx] = emb[(size_t)a * Hn + u];
  if (u == 0) mask[b] = mask[b] * (a == 0 ? 0.f : 1.f);
}

extern "C" void kernel_launch(void* const* d_in, const int* in_sizes, int n_in,
                              void* d_out, int out_size, void* d_ws, size_t ws_size,
                              hipStream_t stream) {
  const float* img  = (const float*)d_in[0];
  const float* emb  = (const float*)d_in[1];
  const float* fc1w = (const float*)d_in[2];
  const float* fc1b = (const float*)d_in[3];
  const float* wih  = (const float*)d_in[4];
  const float* whh  = (const float*)d_in[5];
  const float* bih  = (const float*)d_in[6];
  const float* bhh  = (const float*)d_in[7];
  const float* outw = (const float*)d_in[8];
  const float* outb = (const float*)d_in[9];
  float* out = (float*)d_out;

  float* ws = (float*)d_ws;
  float* hA    = ws;                 // B*H
  float* hB    = hA + Bn * Hn;       // B*H
  float* c     = hB + Bn * Hn;       // B*H
  float* x     = c  + Bn * Hn;       // B*H
  float* mask  = x  + Bn * Hn;       // B
  int*   action = (int*)(mask + Bn); // B
  float* gates = (float*)(action + Bn);    // B*4H
  float* logits = gates + (size_t)Bn * G4; // B*V

  // step keys: fold-like split (jax_threefry_partitionable):
  // keys[t] = threefry2x32(key=(0,42), x0=0, x1=t)
  unsigned kk0[Tn], kk1[Tn];
  for (int i = 0; i < Tn; ++i) {
    unsigned y0, y1;
    threefry2x32(0u, 42u, 0u, (unsigned)i, y0, y1);
    kk0[i] = y0; kk1[i] = y1;
  }

  k_mask<<<4, 256, 0, stream>>>(mask);
  k_fc1<<<64, 256, 0, stream>>>(img, fc1w, fc1b, hA, c, x);

  for (int t = 0; t < Tn; ++t) {
    const float* hin = (t & 1) ? hB : hA;
    float* hout = (t & 1) ? hA : hB;
    k_gates<<<(Bn / 128) * (G4 / 64), 256, 0, stream>>>(x, hin, wih, whh, bih, bhh, gates);
    k_update<<<(Bn * Hn) / 256, 256, 0, stream>>>(gates, c, hout);
    k_logits<<<(Bn / 128) * (Vn / 64), 256, 0, stream>>>(hout, outw, outb, logits);
    k_sm<<<Bn, 256, 0, stream>>>(logits, mask, out, action, kk0[t], kk1[t], t);
    k_next<<<(Bn * Hn) / 256, 256, 0, stream>>>(emb, action, x, mask);
  }
}

// Round 4
// 3949.610 us; speedup vs baseline: 4.5125x; 1.5111x over previous
//
#include <hip/hip_runtime.h>
#include <math.h>

#define Bn 1024
#define Dn 512
#define Hn 512
#define Vn 8192
#define Tn 20
#define G4 2048

typedef _Float16 half8 __attribute__((ext_vector_type(8)));
typedef float f32x4 __attribute__((ext_vector_type(4)));

// ---------------- threefry2x32 (JAX-exact, 20 rounds) ----------------
__host__ __device__ __forceinline__ void threefry2x32(
    unsigned k0, unsigned k1, unsigned x0, unsigned x1,
    unsigned& y0, unsigned& y1) {
  unsigned ks2 = k0 ^ k1 ^ 0x1BD11BDAu;
#define TF_RND(r) { x0 += x1; x1 = (x1 << (r)) | (x1 >> (32 - (r))); x1 ^= x0; }
  x0 += k0; x1 += k1;
  TF_RND(13) TF_RND(15) TF_RND(26) TF_RND(6)
  x0 += k1; x1 += ks2 + 1u;
  TF_RND(17) TF_RND(29) TF_RND(16) TF_RND(24)
  x0 += ks2; x1 += k0 + 2u;
  TF_RND(13) TF_RND(15) TF_RND(26) TF_RND(6)
  x0 += k0; x1 += k1 + 3u;
  TF_RND(17) TF_RND(29) TF_RND(16) TF_RND(24)
  x0 += k1; x1 += ks2 + 4u;
  TF_RND(13) TF_RND(15) TF_RND(26) TF_RND(6)
  x0 += ks2; x1 += k0 + 5u;
#undef TF_RND
  y0 = x0; y1 = x1;
}

// f32 -> f16 hi/lo split. lo scaled by 2^11 to stay in f16 normal range.
__device__ __forceinline__ void split16(float v, _Float16& hi, _Float16& lo) {
  float h = (fabsf(v) < 6.2e-5f) ? 0.f : (float)(_Float16)v;  // keep hi out of f16-denorm
  hi = (_Float16)h;
  lo = (_Float16)((v - h) * 2048.0f);
}

// ---------------- weight split prep (runs once) ----------------
__global__ void k_prep(const float* __restrict__ w, _Float16* __restrict__ hi,
                       _Float16* __restrict__ lo, int n) {
  int i = blockIdx.x * blockDim.x + threadIdx.x;
  if (i >= n) return;
  split16(w[i], hi[i], lo[i]);
}

__global__ void k_mask(float* __restrict__ mask) {
  int i = blockIdx.x * blockDim.x + threadIdx.x;
  if (i < Bn) mask[i] = 1.f;
}

// ---------------- fp16x3 MFMA block GEMM segment ----------------
// C[128x128] += A[128x512] * W[128x512]^T over one K=512 segment.
// acc_h: hi*hi; acc_c: hi*lo + lo*hi (scaled 2^11); final = acc_h + acc_c/2048.
__device__ __forceinline__ void mm_seg(
    const _Float16* __restrict__ Ahs, const _Float16* __restrict__ Als,
    const _Float16* __restrict__ Bhs, const _Float16* __restrict__ Bls,
    int bm, int bn, int tid,
    f32x4 acch[4][4], f32x4 accc[4][4],
    _Float16 (*Ah)[40], _Float16 (*Al)[40],
    _Float16 (*Bh)[40], _Float16 (*Bl)[40]) {
  int lane = tid & 63, wid = tid >> 6;
  int wr = (wid >> 1) << 6, wc = (wid & 1) << 6;
  int fr = lane & 15, kb = (lane >> 4) << 3;
  for (int k0 = 0; k0 < 512; k0 += 32) {
#pragma unroll
    for (int it = 0; it < 2; ++it) {
      int cid = (it << 8) + tid;
      int r = cid >> 2, sg = (cid & 3) << 3;
      size_t ga = (size_t)(bm + r) * 512 + k0 + sg;
      size_t gb = (size_t)(bn + r) * 512 + k0 + sg;
      *(half8*)&Ah[r][sg] = *(const half8*)(Ahs + ga);
      *(half8*)&Al[r][sg] = *(const half8*)(Als + ga);
      *(half8*)&Bh[r][sg] = *(const half8*)(Bhs + gb);
      *(half8*)&Bl[r][sg] = *(const half8*)(Bls + gb);
    }
    __syncthreads();
    half8 ah[4], al[4], bh[4], bl[4];
#pragma unroll
    for (int i = 0; i < 4; ++i) {
      ah[i] = *(const half8*)&Ah[wr + i * 16 + fr][kb];
      al[i] = *(const half8*)&Al[wr + i * 16 + fr][kb];
      bh[i] = *(const half8*)&Bh[wc + i * 16 + fr][kb];
      bl[i] = *(const half8*)&Bl[wc + i * 16 + fr][kb];
    }
#pragma unroll
    for (int mi = 0; mi < 4; ++mi)
#pragma unroll
      for (int ni = 0; ni < 4; ++ni) {
        acch[mi][ni] = __builtin_amdgcn_mfma_f32_16x16x32_f16(ah[mi], bh[ni], acch[mi][ni], 0, 0, 0);
        accc[mi][ni] = __builtin_amdgcn_mfma_f32_16x16x32_f16(ah[mi], bl[ni], accc[mi][ni], 0, 0, 0);
        accc[mi][ni] = __builtin_amdgcn_mfma_f32_16x16x32_f16(al[mi], bh[ni], accc[mi][ni], 0, 0, 0);
      }
    __syncthreads();
  }
}

#define MM_PROLOGUE                                  \
  __shared__ _Float16 Ah[128][40], Al[128][40];      \
  __shared__ _Float16 Bh[128][40], Bl[128][40];      \
  int tid = threadIdx.x;                             \
  f32x4 acch[4][4] = {};                             \
  f32x4 accc[4][4] = {};

#define MM_EPILOGUE_IDX                              \
  int lane = tid & 63, wid = tid >> 6;               \
  int wr = (wid >> 1) << 6, wc = (wid & 1) << 6;     \
  int orow = (lane >> 4) << 2, ocol = lane & 15;

// ---------------- gates = x@wih^T + bih + h@whh^T + bhh ----------------
__global__ void __launch_bounds__(256) k_gates(
    const _Float16* __restrict__ xh, const _Float16* __restrict__ xl,
    const _Float16* __restrict__ hh, const _Float16* __restrict__ hl,
    const _Float16* __restrict__ wihh, const _Float16* __restrict__ wihl,
    const _Float16* __restrict__ whhh, const _Float16* __restrict__ whhl,
    const float* __restrict__ bih, const float* __restrict__ bhh,
    float* __restrict__ gates) {
  int bm = (blockIdx.x >> 4) << 7;   // 8 m-blocks
  int bn = (blockIdx.x & 15) << 7;   // 16 n-blocks (G4=2048)
  MM_PROLOGUE
  mm_seg(xh, xl, wihh, wihl, bm, bn, tid, acch, accc, Ah, Al, Bh, Bl);
  mm_seg(hh, hl, whhh, whhl, bm, bn, tid, acch, accc, Ah, Al, Bh, Bl);
  MM_EPILOGUE_IDX
#pragma unroll
  for (int mi = 0; mi < 4; ++mi)
#pragma unroll
    for (int ni = 0; ni < 4; ++ni) {
      int colg = bn + wc + ni * 16 + ocol;
      float bsum = bih[colg] + bhh[colg];
#pragma unroll
      for (int r = 0; r < 4; ++r) {
        int rowg = bm + wr + mi * 16 + orow + r;
        gates[(size_t)rowg * G4 + colg] =
            acch[mi][ni][r] + accc[mi][ni][r] * (1.0f / 2048.0f) + bsum;
      }
    }
}

// ---------------- logits = h@out_w^T + out_b ----------------
__global__ void __launch_bounds__(256) k_logits(
    const _Float16* __restrict__ hh, const _Float16* __restrict__ hl,
    const _Float16* __restrict__ outwh, const _Float16* __restrict__ outwl,
    const float* __restrict__ outb, float* __restrict__ logits) {
  int bm = (blockIdx.x >> 6) << 7;   // 8 m-blocks
  int bn = (blockIdx.x & 63) << 7;   // 64 n-blocks (V=8192)
  MM_PROLOGUE
  mm_seg(hh, hl, outwh, outwl, bm, bn, tid, acch, accc, Ah, Al, Bh, Bl);
  MM_EPILOGUE_IDX
#pragma unroll
  for (int mi = 0; mi < 4; ++mi)
#pragma unroll
    for (int ni = 0; ni < 4; ++ni) {
      int colg = bn + wc + ni * 16 + ocol;
      float bv = outb[colg];
#pragma unroll
      for (int r = 0; r < 4; ++r) {
        int rowg = bm + wr + mi * 16 + orow + r;
        logits[(size_t)rowg * Vn + colg] =
            acch[mi][ni][r] + accc[mi][ni][r] * (1.0f / 2048.0f) + bv;
      }
    }
}

// ---------------- f32 register-tiled GEMM core (k_fc1 only, runs once) ----
__device__ __forceinline__ void gemm_seg(
    const float* __restrict__ A, int lda, const float* __restrict__ W, int ldw,
    int bm, int bn, int tid, int tm8, int tn4,
    float (*As)[132], float (*Bs)[68], float acc[8][4]) {
  for (int k0 = 0; k0 < 512; k0 += 16) {
#pragma unroll
    for (int it = 0; it < 2; ++it) {
      int g = (it << 8) + tid;
      int m = g >> 2, kq = g & 3;
      const float4 v = *(const float4*)(A + (size_t)(bm + m) * lda + k0 + (kq << 2));
      As[(kq << 2) + 0][m] = v.x; As[(kq << 2) + 1][m] = v.y;
      As[(kq << 2) + 2][m] = v.z; As[(kq << 2) + 3][m] = v.w;
    }
    {
      int m = tid >> 2, kq = tid & 3;
      const float4 v = *(const float4*)(W + (size_t)(bn + m) * ldw + k0 + (kq << 2));
      Bs[(kq << 2) + 0][m] = v.x; Bs[(kq << 2) + 1][m] = v.y;
      Bs[(kq << 2) + 2][m] = v.z; Bs[(kq << 2) + 3][m] = v.w;
    }
    __syncthreads();
#pragma unroll
    for (int k = 0; k < 16; ++k) {
      const float4 a0 = *(const float4*)&As[k][tm8];
      const float4 a1 = *(const float4*)&As[k][tm8 + 4];
      const float4 bv = *(const float4*)&Bs[k][tn4];
      float av[8] = {a0.x, a0.y, a0.z, a0.w, a1.x, a1.y, a1.z, a1.w};
      float bw[4] = {bv.x, bv.y, bv.z, bv.w};
#pragma unroll
      for (int i = 0; i < 8; ++i)
#pragma unroll
        for (int j = 0; j < 4; ++j)
          acc[i][j] = fmaf(av[i], bw[j], acc[i][j]);
    }
    __syncthreads();
  }
}

// ---------------- init: h0 = relu(img@fc1^T + b) -> hh/hl; c=0; x=0 ----------------
__global__ void __launch_bounds__(256) k_fc1(
    const float* __restrict__ img, const float* __restrict__ fc1w,
    const float* __restrict__ fc1b,
    _Float16* __restrict__ hh, _Float16* __restrict__ hl,
    _Float16* __restrict__ xh, _Float16* __restrict__ xl,
    float* __restrict__ c) {
  __shared__ float As[16][132];
  __shared__ float Bs[16][68];
  int tid = threadIdx.x;
  int tm8 = (tid >> 4) << 3;
  int tn4 = (tid & 15) << 2;
  float acc[8][4] = {};
  int bm = (blockIdx.x >> 3) << 7;
  int bn = (blockIdx.x & 7) << 6;
  gemm_seg(img, Dn, fc1w, Dn, bm, bn, tid, tm8, tn4, As, Bs, acc);
  const float4 b4 = *(const float4*)(fc1b + bn + tn4);
  float bb[4] = {b4.x, b4.y, b4.z, b4.w};
#pragma unroll
  for (int i = 0; i < 8; ++i) {
    size_t off = (size_t)(bm + tm8 + i) * Hn + bn + tn4;
#pragma unroll
    for (int j = 0; j < 4; ++j) {
      float hv = fmaxf(acc[i][j] + bb[j], 0.f);
      split16(hv, hh[off + j], hl[off + j]);
      xh[off + j] = (_Float16)0.f;
      xl[off + j] = (_Float16)0.f;
      c[off + j] = 0.f;
    }
  }
}

// ---------------- LSTM cell pointwise update ----------------
__global__ void k_update(const float* __restrict__ gates, float* __restrict__ c,
                         _Float16* __restrict__ hh, _Float16* __restrict__ hl) {
  int idx = blockIdx.x * blockDim.x + threadIdx.x;  // B*H
  int b = idx >> 9, u = idx & 511;
  const float* gr = gates + (size_t)b * G4;
  float gi = gr[u], gf = gr[Hn + u], gg = gr[2 * Hn + u], go = gr[3 * Hn + u];
  double si = 1.0 / (1.0 + exp(-(double)gi));
  double sf = 1.0 / (1.0 + exp(-(double)gf));
  double tg = tanh((double)gg);
  double so = 1.0 / (1.0 + exp(-(double)go));
  double cold = (double)c[idx];
  float cn = (float)(sf * cold + si * tg);
  c[idx] = cn;
  float hv = (float)(so * tanh((double)cn));
  split16(hv, hh[idx], hl[idx]);
}

// ---------------- fused softmax + gumbel-argmax + outputs (one block per row) ----------------
// Partitionable threefry: bits(j) = y0 ^ y1, (y0,y1) = threefry(step_key, 0, j), j = b*V+v.
__global__ void __launch_bounds__(256) k_sm(
    const float* __restrict__ logits, const float* __restrict__ mask,
    float* __restrict__ out_base, int* __restrict__ action,
    unsigned k0, unsigned k1, int t) {
  __shared__ __align__(16) float row[Vn];
  __shared__ float rf[256];
  __shared__ int ri[256];
  __shared__ double rd[256];
  int b = blockIdx.x, tid = threadIdx.x;
  const float4* src = (const float4*)(logits + (size_t)b * Vn);
  float4* dst = (float4*)row;
  for (int i = tid; i < Vn / 4; i += 256) dst[i] = src[i];
  __syncthreads();

  // pass 1: row max + gumbel argmax (first-index tiebreak)
  float m = -INFINITY, best = -INFINITY;
  int bidx = Vn;
  for (int v = tid; v < Vn; v += 256) {
    float lg = row[v];
    m = fmaxf(m, lg);
    unsigned j = (unsigned)(b * Vn + v);
    unsigned y0, y1;
    threefry2x32(k0, k1, 0u, j, y0, y1);
    unsigned bits = y0 ^ y1;
    float uf = __uint_as_float((bits >> 9) | 0x3F800000u) - 1.0f;
    uf = fmaxf(uf, 1.17549435e-38f);           // u = max(tiny, f)
    float inner = (float)(-log((double)uf));    // f32-rounded inner -log(u)
    float g = (float)(-log((double)inner));     // f32-rounded gumbel
    float val = lg + g;
    if (val > best) { best = val; bidx = v; }   // ascending v -> first max kept
  }
  rf[tid] = m;
  __syncthreads();
  for (int s = 128; s > 0; s >>= 1) {
    if (tid < s) rf[tid] = fmaxf(rf[tid], rf[tid + s]);
    __syncthreads();
  }
  float rowmax = rf[0];
  __syncthreads();
  rf[tid] = best; ri[tid] = bidx;
  __syncthreads();
  for (int s = 128; s > 0; s >>= 1) {
    if (tid < s) {
      float v2 = rf[tid + s]; int i2 = ri[tid + s];
      if (v2 > rf[tid] || (v2 == rf[tid] && i2 < ri[tid])) { rf[tid] = v2; ri[tid] = i2; }
    }
    __syncthreads();
  }
  int act = ri[0];

  // pass 2: sum exp(x - m), f32 exp + f64 adds
  double sacc = 0.0;
  for (int v = tid; v < Vn; v += 256) sacc += (double)expf(row[v] - rowmax);
  rd[tid] = sacc;
  __syncthreads();
  for (int s = 128; s > 0; s >>= 1) {
    if (tid < s) rd[tid] += rd[tid + s];
    __syncthreads();
  }
  double lse = log(rd[0]);
  float mk = mask[b];
  __syncthreads();

  // pass 3: logp, p, probs, entropy, lp
  float* probs = out_base + 3 * Bn * Tn + ((size_t)(b * Tn + t)) * Vn;
  double entacc = 0.0;
  for (int v = tid; v < Vn; v += 256) {
    float sh = row[v] - rowmax;
    float logp = (float)((double)sh - lse);
    float p = expf(logp);
    probs[v] = p * mk;
    entacc += (double)(p * logp);
    if (v == act) out_base[Bn * Tn + b * Tn + t] = logp * mk;  // lps
  }
  rd[tid] = entacc;
  __syncthreads();
  for (int s = 128; s > 0; s >>= 1) {
    if (tid < s) rd[tid] += rd[tid + s];
    __syncthreads();
  }
  if (tid == 0) {
    out_base[2 * Bn * Tn + b * Tn + t] = (float)(-rd[0]) * mk;  // ents
    out_base[b * Tn + t] = (float)act;                          // msgs
    action[b] = act;
  }
}

// ---------------- next input: x = emb[action] (split), mask update (eos=0) ----------------
__global__ void k_next(const float* __restrict__ emb, const int* __restrict__ action,
                       _Float16* __restrict__ xh, _Float16* __restrict__ xl,
                       float* __restrict__ mask) {
  int idx = blockIdx.x * blockDim.x + threadIdx.x;  // B*H
  int b = idx >> 9, u = idx & 511;
  int a = action[b];
  float v = emb[(size_t)a * Hn + u];
  split16(v, xh[idx], xl[idx]);
  if (u == 0) mask[b] = mask[b] * (a == 0 ? 0.f : 1.f);
}

extern "C" void kernel_launch(void* const* d_in, const int* in_sizes, int n_in,
                              void* d_out, int out_size, void* d_ws, size_t ws_size,
                              hipStream_t stream) {
  const float* img  = (const float*)d_in[0];
  const float* emb  = (const float*)d_in[1];
  const float* fc1w = (const float*)d_in[2];
  const float* fc1b = (const float*)d_in[3];
  const float* wih  = (const float*)d_in[4];
  const float* whh  = (const float*)d_in[5];
  const float* bih  = (const float*)d_in[6];
  const float* bhh  = (const float*)d_in[7];
  const float* outw = (const float*)d_in[8];
  const float* outb = (const float*)d_in[9];
  float* out = (float*)d_out;

  float* ws = (float*)d_ws;
  float* c      = ws;                          // B*H
  float* mask   = c + Bn * Hn;                 // B
  int*   action = (int*)(mask + Bn);           // B
  float* gates  = (float*)(action + Bn);       // B*G4
  float* logits = gates + (size_t)Bn * G4;     // B*V
  _Float16* wihh = (_Float16*)(logits + (size_t)Bn * Vn);
  _Float16* wihl = wihh + (size_t)G4 * Hn;
  _Float16* whhh = wihl + (size_t)G4 * Hn;
  _Float16* whhl = whhh + (size_t)G4 * Hn;
  _Float16* outwh = whhl + (size_t)G4 * Hn;
  _Float16* outwl = outwh + (size_t)Vn * Hn;
  _Float16* xh = outwl + (size_t)Vn * Hn;
  _Float16* xl = xh + Bn * Hn;
  _Float16* hh = xl + Bn * Hn;
  _Float16* hl = hh + Bn * Hn;

  // step keys: fold-like split (jax_threefry_partitionable):
  // keys[t] = threefry2x32(key=(0,42), x0=0, x1=t)
  unsigned kk0[Tn], kk1[Tn];
  for (int i = 0; i < Tn; ++i) {
    unsigned y0, y1;
    threefry2x32(0u, 42u, 0u, (unsigned)i, y0, y1);
    kk0[i] = y0; kk1[i] = y1;
  }

  // one-time weight splits
  k_prep<<<(G4 * Hn) / 256, 256, 0, stream>>>(wih, wihh, wihl, G4 * Hn);
  k_prep<<<(G4 * Hn) / 256, 256, 0, stream>>>(whh, whhh, whhl, G4 * Hn);
  k_prep<<<(Vn * Hn) / 256, 256, 0, stream>>>(outw, outwh, outwl, Vn * Hn);
  k_mask<<<4, 256, 0, stream>>>(mask);
  k_fc1<<<64, 256, 0, stream>>>(img, fc1w, fc1b, hh, hl, xh, xl, c);

  for (int t = 0; t < Tn; ++t) {
    k_gates<<<(Bn / 128) * (G4 / 128), 256, 0, stream>>>(
        xh, xl, hh, hl, wihh, wihl, whhh, whhl, bih, bhh, gates);
    k_update<<<(Bn * Hn) / 256, 256, 0, stream>>>(gates, c, hh, hl);
    k_logits<<<(Bn / 128) * (Vn / 128), 256, 0, stream>>>(
        hh, hl, outwh, outwl, outb, logits);
    k_sm<<<Bn, 256, 0, stream>>>(logits, mask, out, action, kk0[t], kk1[t], t);
    k_next<<<(Bn * Hn) / 256, 256, 0, stream>>>(emb, action, xh, xl, mask);
  }
}

// Round 5
// 3575.470 us; speedup vs baseline: 4.9847x; 1.1046x over previous
//
#include <hip/hip_runtime.h>
#include <math.h>

#define Bn 1024
#define Dn 512
#define Hn 512
#define Vn 8192
#define Tn 20
#define G4 2048

typedef _Float16 half8 __attribute__((ext_vector_type(8)));
typedef float f32x4 __attribute__((ext_vector_type(4)));

// ---------------- threefry2x32 (JAX-exact, 20 rounds) ----------------
__host__ __device__ __forceinline__ void threefry2x32(
    unsigned k0, unsigned k1, unsigned x0, unsigned x1,
    unsigned& y0, unsigned& y1) {
  unsigned ks2 = k0 ^ k1 ^ 0x1BD11BDAu;
#define TF_RND(r) { x0 += x1; x1 = (x1 << (r)) | (x1 >> (32 - (r))); x1 ^= x0; }
  x0 += k0; x1 += k1;
  TF_RND(13) TF_RND(15) TF_RND(26) TF_RND(6)
  x0 += k1; x1 += ks2 + 1u;
  TF_RND(17) TF_RND(29) TF_RND(16) TF_RND(24)
  x0 += ks2; x1 += k0 + 2u;
  TF_RND(13) TF_RND(15) TF_RND(26) TF_RND(6)
  x0 += k0; x1 += k1 + 3u;
  TF_RND(17) TF_RND(29) TF_RND(16) TF_RND(24)
  x0 += k1; x1 += ks2 + 4u;
  TF_RND(13) TF_RND(15) TF_RND(26) TF_RND(6)
  x0 += ks2; x1 += k0 + 5u;
#undef TF_RND
  y0 = x0; y1 = x1;
}

// f32 -> f16 hi/lo split. lo scaled by 2^11 to stay in f16 normal range.
__device__ __forceinline__ void split16(float v, _Float16& hi, _Float16& lo) {
  float h = (fabsf(v) < 6.2e-5f) ? 0.f : (float)(_Float16)v;  // keep hi out of f16-denorm
  hi = (_Float16)h;
  lo = (_Float16)((v - h) * 2048.0f);
}

// ---------------- prep kernels (run every call; idempotent) ----------------
__global__ void k_prep(const float* __restrict__ w, _Float16* __restrict__ hi,
                       _Float16* __restrict__ lo, int n) {
  int i = blockIdx.x * blockDim.x + threadIdx.x;
  if (i >= n) return;
  split16(w[i], hi[i], lo[i]);
}

// gate-interleaved permutation: dst row u*4+g  <-  src row g*512+u
__global__ void k_prep_perm(const float* __restrict__ w, _Float16* __restrict__ hi,
                            _Float16* __restrict__ lo) {
  int i = blockIdx.x * blockDim.x + threadIdx.x;  // G4*Hn
  int rp = i >> 9, k = i & 511;
  int u = rp >> 2, g = rp & 3;
  split16(w[(size_t)((g << 9) + u) * 512 + k], hi[i], lo[i]);
}

__global__ void k_prep_bias(const float* __restrict__ bih, const float* __restrict__ bhh,
                            float* __restrict__ bp) {
  int i = blockIdx.x * blockDim.x + threadIdx.x;  // G4
  if (i >= G4) return;
  int u = i >> 2, g = i & 3;
  bp[i] = bih[(g << 9) + u] + bhh[(g << 9) + u];
}

__global__ void k_mask(float* __restrict__ mask) {
  int i = blockIdx.x * blockDim.x + threadIdx.x;
  if (i < Bn) mask[i] = 1.f;
}

// ---------------- fp16x3 MFMA segment, 128x128 tile (k_logits) ----------------
__device__ __forceinline__ void mm_seg(
    const _Float16* __restrict__ Ahs, const _Float16* __restrict__ Als,
    const _Float16* __restrict__ Bhs, const _Float16* __restrict__ Bls,
    int bm, int bn, int tid,
    f32x4 acch[4][4], f32x4 accc[4][4],
    _Float16 (*Ah)[40], _Float16 (*Al)[40],
    _Float16 (*Bh)[40], _Float16 (*Bl)[40]) {
  int lane = tid & 63, wid = tid >> 6;
  int wr = (wid >> 1) << 6, wc = (wid & 1) << 6;
  int fr = lane & 15, kb = (lane >> 4) << 3;
  for (int k0 = 0; k0 < 512; k0 += 32) {
#pragma unroll
    for (int it = 0; it < 2; ++it) {
      int cid = (it << 8) + tid;
      int r = cid >> 2, sg = (cid & 3) << 3;
      size_t ga = (size_t)(bm + r) * 512 + k0 + sg;
      size_t gb = (size_t)(bn + r) * 512 + k0 + sg;
      *(half8*)&Ah[r][sg] = *(const half8*)(Ahs + ga);
      *(half8*)&Al[r][sg] = *(const half8*)(Als + ga);
      *(half8*)&Bh[r][sg] = *(const half8*)(Bhs + gb);
      *(half8*)&Bl[r][sg] = *(const half8*)(Bls + gb);
    }
    __syncthreads();
    half8 ah[4], al[4], bh[4], bl[4];
#pragma unroll
    for (int i = 0; i < 4; ++i) {
      ah[i] = *(const half8*)&Ah[wr + i * 16 + fr][kb];
      al[i] = *(const half8*)&Al[wr + i * 16 + fr][kb];
      bh[i] = *(const half8*)&Bh[wc + i * 16 + fr][kb];
      bl[i] = *(const half8*)&Bl[wc + i * 16 + fr][kb];
    }
#pragma unroll
    for (int mi = 0; mi < 4; ++mi)
#pragma unroll
      for (int ni = 0; ni < 4; ++ni) {
        acch[mi][ni] = __builtin_amdgcn_mfma_f32_16x16x32_f16(ah[mi], bh[ni], acch[mi][ni], 0, 0, 0);
        accc[mi][ni] = __builtin_amdgcn_mfma_f32_16x16x32_f16(ah[mi], bl[ni], accc[mi][ni], 0, 0, 0);
        accc[mi][ni] = __builtin_amdgcn_mfma_f32_16x16x32_f16(al[mi], bh[ni], accc[mi][ni], 0, 0, 0);
      }
    __syncthreads();
  }
}

// ---------------- fp16x3 MFMA segment, 128x64 tile (k_gates) ----------------
__device__ __forceinline__ void mm_seg64(
    const _Float16* __restrict__ Ahs, const _Float16* __restrict__ Als,
    const _Float16* __restrict__ Bhs, const _Float16* __restrict__ Bls,
    int bm, int bn, int tid,
    f32x4 acch[4][2], f32x4 accc[4][2],
    _Float16 (*Ah)[40], _Float16 (*Al)[40],
    _Float16 (*Bh)[40], _Float16 (*Bl)[40]) {
  int lane = tid & 63, wid = tid >> 6;
  int wr = (wid >> 1) << 6, wc = (wid & 1) << 5;
  int fr = lane & 15, kb = (lane >> 4) << 3;
  for (int k0 = 0; k0 < 512; k0 += 32) {
#pragma unroll
    for (int it = 0; it < 2; ++it) {
      int cid = (it << 8) + tid;
      int r = cid >> 2, sg = (cid & 3) << 3;
      size_t ga = (size_t)(bm + r) * 512 + k0 + sg;
      *(half8*)&Ah[r][sg] = *(const half8*)(Ahs + ga);
      *(half8*)&Al[r][sg] = *(const half8*)(Als + ga);
    }
    {
      int r = tid >> 2, sg = (tid & 3) << 3;
      size_t gb = (size_t)(bn + r) * 512 + k0 + sg;
      *(half8*)&Bh[r][sg] = *(const half8*)(Bhs + gb);
      *(half8*)&Bl[r][sg] = *(const half8*)(Bls + gb);
    }
    __syncthreads();
    half8 ah[4], al[4], bh[2], bl[2];
#pragma unroll
    for (int i = 0; i < 4; ++i) {
      ah[i] = *(const half8*)&Ah[wr + i * 16 + fr][kb];
      al[i] = *(const half8*)&Al[wr + i * 16 + fr][kb];
    }
#pragma unroll
    for (int i = 0; i < 2; ++i) {
      bh[i] = *(const half8*)&Bh[wc + i * 16 + fr][kb];
      bl[i] = *(const half8*)&Bl[wc + i * 16 + fr][kb];
    }
#pragma unroll
    for (int mi = 0; mi < 4; ++mi)
#pragma unroll
      for (int ni = 0; ni < 2; ++ni) {
        acch[mi][ni] = __builtin_amdgcn_mfma_f32_16x16x32_f16(ah[mi], bh[ni], acch[mi][ni], 0, 0, 0);
        accc[mi][ni] = __builtin_amdgcn_mfma_f32_16x16x32_f16(ah[mi], bl[ni], accc[mi][ni], 0, 0, 0);
        accc[mi][ni] = __builtin_amdgcn_mfma_f32_16x16x32_f16(al[mi], bh[ni], accc[mi][ni], 0, 0, 0);
      }
    __syncthreads();
  }
}

// ---------------- gates GEMM (permuted, 128x64 tile) + fused LSTM cell update ----
__global__ void __launch_bounds__(256) k_gates(
    const _Float16* __restrict__ xh, const _Float16* __restrict__ xl,
    const _Float16* __restrict__ hih, const _Float16* __restrict__ hil,
    const _Float16* __restrict__ wph, const _Float16* __restrict__ wpl,
    const _Float16* __restrict__ vph, const _Float16* __restrict__ vpl,
    const float* __restrict__ biasp, float* __restrict__ c,
    _Float16* __restrict__ hoh, _Float16* __restrict__ hol) {
  __shared__ _Float16 Ah[128][40], Al[128][40];
  __shared__ _Float16 Bh[64][40], Bl[64][40];
  __shared__ float gtile[128][68];
  int tid = threadIdx.x;
  f32x4 acch[4][2] = {};
  f32x4 accc[4][2] = {};
  int bm = (blockIdx.x >> 5) << 7;   // 8 m-blocks of 128 batch rows
  int bn = (blockIdx.x & 31) << 6;   // 32 n-blocks of 64 cols (16 u's x 4 gates)
  mm_seg64(xh, xl, wph, wpl, bm, bn, tid, acch, accc, Ah, Al, Bh, Bl);
  mm_seg64(hih, hil, vph, vpl, bm, bn, tid, acch, accc, Ah, Al, Bh, Bl);
  // epilogue -> gtile
  int lane = tid & 63, wid = tid >> 6;
  int wr = (wid >> 1) << 6, wc = (wid & 1) << 5;
  int orow = (lane >> 4) << 2, ocol = lane & 15;
#pragma unroll
  for (int mi = 0; mi < 4; ++mi)
#pragma unroll
    for (int ni = 0; ni < 2; ++ni) {
      int col = wc + ni * 16 + ocol;
      float bsum = biasp[bn + col];
#pragma unroll
      for (int r = 0; r < 4; ++r) {
        int row = wr + mi * 16 + orow + r;
        gtile[row][col] = acch[mi][ni][r] + accc[mi][ni][r] * (1.0f / 2048.0f) + bsum;
      }
    }
  __syncthreads();
  // fused cell update: 128 rows x 16 u's = 2048 pairs, 8 per thread
  int u0 = bn >> 2;
#pragma unroll
  for (int j = 0; j < 8; ++j) {
    int idx = tid + (j << 8);
    int row = idx >> 4, ul = idx & 15;
    float4 gt = *(const float4*)&gtile[row][ul << 2];  // i,f,g,o
    size_t cidx = (size_t)(bm + row) * Hn + u0 + ul;
    double si = 1.0 / (1.0 + exp(-(double)gt.x));
    double sf = 1.0 / (1.0 + exp(-(double)gt.y));
    double tg = tanh((double)gt.z);
    double so = 1.0 / (1.0 + exp(-(double)gt.w));
    float cn = (float)(sf * (double)c[cidx] + si * tg);
    c[cidx] = cn;
    float hv = (float)(so * tanh((double)cn));
    split16(hv, hoh[cidx], hol[cidx]);
  }
}

// ---------------- logits = h@out_w^T + out_b (128x128 tile) ----------------
__global__ void __launch_bounds__(256) k_logits(
    const _Float16* __restrict__ hh, const _Float16* __restrict__ hl,
    const _Float16* __restrict__ outwh, const _Float16* __restrict__ outwl,
    const float* __restrict__ outb, float* __restrict__ logits) {
  __shared__ _Float16 Ah[128][40], Al[128][40];
  __shared__ _Float16 Bh[128][40], Bl[128][40];
  int tid = threadIdx.x;
  f32x4 acch[4][4] = {};
  f32x4 accc[4][4] = {};
  int bm = (blockIdx.x >> 6) << 7;   // 8 m-blocks
  int bn = (blockIdx.x & 63) << 7;   // 64 n-blocks (V=8192)
  mm_seg(hh, hl, outwh, outwl, bm, bn, tid, acch, accc, Ah, Al, Bh, Bl);
  int lane = tid & 63, wid = tid >> 6;
  int wr = (wid >> 1) << 6, wc = (wid & 1) << 6;
  int orow = (lane >> 4) << 2, ocol = lane & 15;
#pragma unroll
  for (int mi = 0; mi < 4; ++mi)
#pragma unroll
    for (int ni = 0; ni < 4; ++ni) {
      int colg = bn + wc + ni * 16 + ocol;
      float bv = outb[colg];
#pragma unroll
      for (int r = 0; r < 4; ++r) {
        int rowg = bm + wr + mi * 16 + orow + r;
        logits[(size_t)rowg * Vn + colg] =
            acch[mi][ni][r] + accc[mi][ni][r] * (1.0f / 2048.0f) + bv;
      }
    }
}

// ---------------- f32 register-tiled GEMM (k_fc1 only, runs once) ----------
__device__ __forceinline__ void gemm_seg(
    const float* __restrict__ A, int lda, const float* __restrict__ W, int ldw,
    int bm, int bn, int tid, int tm8, int tn4,
    float (*As)[132], float (*Bs)[68], float acc[8][4]) {
  for (int k0 = 0; k0 < 512; k0 += 16) {
#pragma unroll
    for (int it = 0; it < 2; ++it) {
      int g = (it << 8) + tid;
      int m = g >> 2, kq = g & 3;
      const float4 v = *(const float4*)(A + (size_t)(bm + m) * lda + k0 + (kq << 2));
      As[(kq << 2) + 0][m] = v.x; As[(kq << 2) + 1][m] = v.y;
      As[(kq << 2) + 2][m] = v.z; As[(kq << 2) + 3][m] = v.w;
    }
    {
      int m = tid >> 2, kq = tid & 3;
      const float4 v = *(const float4*)(W + (size_t)(bn + m) * ldw + k0 + (kq << 2));
      Bs[(kq << 2) + 0][m] = v.x; Bs[(kq << 2) + 1][m] = v.y;
      Bs[(kq << 2) + 2][m] = v.z; Bs[(kq << 2) + 3][m] = v.w;
    }
    __syncthreads();
#pragma unroll
    for (int k = 0; k < 16; ++k) {
      const float4 a0 = *(const float4*)&As[k][tm8];
      const float4 a1 = *(const float4*)&As[k][tm8 + 4];
      const float4 bv = *(const float4*)&Bs[k][tn4];
      float av[8] = {a0.x, a0.y, a0.z, a0.w, a1.x, a1.y, a1.z, a1.w};
      float bw[4] = {bv.x, bv.y, bv.z, bv.w};
#pragma unroll
      for (int i = 0; i < 8; ++i)
#pragma unroll
        for (int j = 0; j < 4; ++j)
          acc[i][j] = fmaf(av[i], bw[j], acc[i][j]);
    }
    __syncthreads();
  }
}

// ---------------- init: h0 = relu(img@fc1^T + b) -> hh/hl; c=0; x=0 --------
__global__ void __launch_bounds__(256) k_fc1(
    const float* __restrict__ img, const float* __restrict__ fc1w,
    const float* __restrict__ fc1b,
    _Float16* __restrict__ hh, _Float16* __restrict__ hl,
    _Float16* __restrict__ xh, _Float16* __restrict__ xl,
    float* __restrict__ c) {
  __shared__ float As[16][132];
  __shared__ float Bs[16][68];
  int tid = threadIdx.x;
  int tm8 = (tid >> 4) << 3;
  int tn4 = (tid & 15) << 2;
  float acc[8][4] = {};
  int bm = (blockIdx.x >> 3) << 7;
  int bn = (blockIdx.x & 7) << 6;
  gemm_seg(img, Dn, fc1w, Dn, bm, bn, tid, tm8, tn4, As, Bs, acc);
  const float4 b4 = *(const float4*)(fc1b + bn + tn4);
  float bb[4] = {b4.x, b4.y, b4.z, b4.w};
#pragma unroll
  for (int i = 0; i < 8; ++i) {
    size_t off = (size_t)(bm + tm8 + i) * Hn + bn + tn4;
#pragma unroll
    for (int j = 0; j < 4; ++j) {
      float hv = fmaxf(acc[i][j] + bb[j], 0.f);
      split16(hv, hh[off + j], hl[off + j]);
      xh[off + j] = (_Float16)0.f;
      xl[off + j] = (_Float16)0.f;
      c[off + j] = 0.f;
    }
  }
}

// ---------------- fused softmax + gumbel-argmax + outputs + next-x ---------
// Partitionable threefry: bits(j) = y0 ^ y1, (y0,y1) = threefry(step_key, 0, j), j = b*V+v.
__global__ void __launch_bounds__(256) k_sm(
    const float* __restrict__ logits, const float* __restrict__ emb,
    float* __restrict__ mask, float* __restrict__ out_base,
    _Float16* __restrict__ xh, _Float16* __restrict__ xl,
    unsigned k0, unsigned k1, int t) {
  __shared__ __align__(16) float row[Vn];
  __shared__ float rf[256];
  __shared__ int ri[256];
  __shared__ double rd[256];
  int b = blockIdx.x, tid = threadIdx.x;
  const float4* src = (const float4*)(logits + (size_t)b * Vn);
  float4* dst = (float4*)row;
  for (int i = tid; i < Vn / 4; i += 256) dst[i] = src[i];
  __syncthreads();

  // pass 1: row max + gumbel argmax (first-index tiebreak)
  float m = -INFINITY, best = -INFINITY;
  int bidx = Vn;
  for (int v = tid; v < Vn; v += 256) {
    float lg = row[v];
    m = fmaxf(m, lg);
    unsigned j = (unsigned)(b * Vn + v);
    unsigned y0, y1;
    threefry2x32(k0, k1, 0u, j, y0, y1);
    unsigned bits = y0 ^ y1;
    float uf = __uint_as_float((bits >> 9) | 0x3F800000u) - 1.0f;
    uf = fmaxf(uf, 1.17549435e-38f);            // u = max(tiny, f)
    float inner = (float)(-log((double)uf));    // f32-rounded inner -log(u)
    float g = (float)(-log((double)inner));     // f32-rounded gumbel
    float val = lg + g;
    if (val > best) { best = val; bidx = v; }   // ascending v -> first max kept
  }
  rf[tid] = m;
  __syncthreads();
  for (int s = 128; s > 0; s >>= 1) {
    if (tid < s) rf[tid] = fmaxf(rf[tid], rf[tid + s]);
    __syncthreads();
  }
  float rowmax = rf[0];
  __syncthreads();
  rf[tid] = best; ri[tid] = bidx;
  __syncthreads();
  for (int s = 128; s > 0; s >>= 1) {
    if (tid < s) {
      float v2 = rf[tid + s]; int i2 = ri[tid + s];
      if (v2 > rf[tid] || (v2 == rf[tid] && i2 < ri[tid])) { rf[tid] = v2; ri[tid] = i2; }
    }
    __syncthreads();
  }
  int act = ri[0];

  // pass 2: sum exp(x - m), f32 exp + f64 adds
  double sacc = 0.0;
  for (int v = tid; v < Vn; v += 256) sacc += (double)expf(row[v] - rowmax);
  rd[tid] = sacc;
  __syncthreads();
  for (int s = 128; s > 0; s >>= 1) {
    if (tid < s) rd[tid] += rd[tid + s];
    __syncthreads();
  }
  double lse = log(rd[0]);
  float mk = mask[b];
  __syncthreads();

  // pass 3 (float4): logp, p, probs, entropy, lp
  float* probs = out_base + 3 * Bn * Tn + ((size_t)(b * Tn + t)) * Vn;
  double entacc = 0.0;
  for (int v0 = tid << 2; v0 < Vn; v0 += 1024) {
    float4 l4 = *(const float4*)&row[v0];
    float lp[4], pp[4];
    lp[0] = (float)((double)(l4.x - rowmax) - lse);
    lp[1] = (float)((double)(l4.y - rowmax) - lse);
    lp[2] = (float)((double)(l4.z - rowmax) - lse);
    lp[3] = (float)((double)(l4.w - rowmax) - lse);
#pragma unroll
    for (int q = 0; q < 4; ++q) {
      pp[q] = expf(lp[q]);
      entacc += (double)(pp[q] * lp[q]);
    }
    float4 o = {pp[0] * mk, pp[1] * mk, pp[2] * mk, pp[3] * mk};
    *(float4*)&probs[v0] = o;
    int d = act - v0;
    if (d >= 0 && d < 4)
      out_base[Bn * Tn + b * Tn + t] = lp[d] * mk;  // lps
  }
  rd[tid] = entacc;
  __syncthreads();
  for (int s = 128; s > 0; s >>= 1) {
    if (tid < s) rd[tid] += rd[tid + s];
    __syncthreads();
  }
  // fused next-input: x = emb[act] (split), mask update (eos=0)
  for (int j = tid; j < Hn; j += 256) {
    float v = emb[(size_t)act * Hn + j];
    split16(v, xh[(size_t)b * Hn + j], xl[(size_t)b * Hn + j]);
  }
  if (tid == 0) {
    out_base[2 * Bn * Tn + b * Tn + t] = (float)(-rd[0]) * mk;  // ents
    out_base[b * Tn + t] = (float)act;                          // msgs
    mask[b] = mk * (act == 0 ? 0.f : 1.f);
  }
}

extern "C" void kernel_launch(void* const* d_in, const int* in_sizes, int n_in,
                              void* d_out, int out_size, void* d_ws, size_t ws_size,
                              hipStream_t stream) {
  const float* img  = (const float*)d_in[0];
  const float* emb  = (const float*)d_in[1];
  const float* fc1w = (const float*)d_in[2];
  const float* fc1b = (const float*)d_in[3];
  const float* wih  = (const float*)d_in[4];
  const float* whh  = (const float*)d_in[5];
  const float* bih  = (const float*)d_in[6];
  const float* bhh  = (const float*)d_in[7];
  const float* outw = (const float*)d_in[8];
  const float* outb = (const float*)d_in[9];
  float* out = (float*)d_out;

  float* ws = (float*)d_ws;
  float* c      = ws;                          // B*H
  float* mask   = c + Bn * Hn;                 // B
  float* biasp  = mask + Bn;                   // G4
  float* logits = biasp + G4;                  // B*V
  _Float16* wph  = (_Float16*)(logits + (size_t)Bn * Vn);  // permuted wih hi
  _Float16* wpl  = wph + (size_t)G4 * Hn;
  _Float16* vph  = wpl + (size_t)G4 * Hn;                  // permuted whh hi
  _Float16* vpl  = vph + (size_t)G4 * Hn;
  _Float16* outwh = vpl + (size_t)G4 * Hn;
  _Float16* outwl = outwh + (size_t)Vn * Hn;
  _Float16* xh = outwl + (size_t)Vn * Hn;
  _Float16* xl = xh + Bn * Hn;
  _Float16* hhA = xl + Bn * Hn;
  _Float16* hlA = hhA + Bn * Hn;
  _Float16* hhB = hlA + Bn * Hn;
  _Float16* hlB = hhB + Bn * Hn;

  // step keys: fold-like split (jax_threefry_partitionable):
  // keys[t] = threefry2x32(key=(0,42), x0=0, x1=t)
  unsigned kk0[Tn], kk1[Tn];
  for (int i = 0; i < Tn; ++i) {
    unsigned y0, y1;
    threefry2x32(0u, 42u, 0u, (unsigned)i, y0, y1);
    kk0[i] = y0; kk1[i] = y1;
  }

  // one-time preps
  k_prep_perm<<<(G4 * Hn) / 256, 256, 0, stream>>>(wih, wph, wpl);
  k_prep_perm<<<(G4 * Hn) / 256, 256, 0, stream>>>(whh, vph, vpl);
  k_prep<<<(Vn * Hn) / 256, 256, 0, stream>>>(outw, outwh, outwl, Vn * Hn);
  k_prep_bias<<<G4 / 256, 256, 0, stream>>>(bih, bhh, biasp);
  k_mask<<<4, 256, 0, stream>>>(mask);
  k_fc1<<<64, 256, 0, stream>>>(img, fc1w, fc1b, hhA, hlA, xh, xl, c);

  for (int t = 0; t < Tn; ++t) {
    const _Float16* hih = (t & 1) ? hhB : hhA;
    const _Float16* hil = (t & 1) ? hlB : hlA;
    _Float16* hoh = (t & 1) ? hhA : hhB;
    _Float16* hol = (t & 1) ? hlA : hlB;
    k_gates<<<(Bn / 128) * (G4 / 64), 256, 0, stream>>>(
        xh, xl, hih, hil, wph, wpl, vph, vpl, biasp, c, hoh, hol);
    k_logits<<<(Bn / 128) * (Vn / 128), 256, 0, stream>>>(
        hoh, hol, outwh, outwl, outb, logits);
    k_sm<<<Bn, 256, 0, stream>>>(logits, emb, mask, out, xh, xl, kk0[t], kk1[t], t);
  }
}